// Round 18
// baseline (642.538 us; speedup 1.0000x reference)
//
#include <hip/hip_runtime.h>
#include <hip/hip_bf16.h>

#define NTOK 8192
#define DIM 1024
#define HID 2816
#define NE 8
#define NSLOT (NTOK*2)
#define BM 128
#define BK 32
#define MAXMT (NSLOT/BM + NE)    // 136 M-tiles @ BM=128 (ffn1)
#define BM2 256
#define BK2 64
#define MAXMT2 (NSLOT/BM2 + NE)  // 72 M-tiles @ BM=256 (ffn2)

typedef float f32x4 __attribute__((ext_vector_type(4)));
typedef __bf16 bf16x8 __attribute__((ext_vector_type(8)));
typedef __bf16 bf16x4 __attribute__((ext_vector_type(4)));

#define MFMA(a,b,c) __builtin_amdgcn_mfma_f32_16x16x32_bf16(a,b,c,0,0,0)
// element index in a linear [rows][32] bf16 block, XOR bank swizzle (R2-proven: 0 conflicts)
#define SWZ(r,g) (((r)<<5) + ((((g) ^ (((r)>>1)&3)))<<3))
#define VMW(N) asm volatile("s_waitcnt vmcnt(" #N ")" ::: "memory")
#define NOP do{}while(0)

__device__ __forceinline__ void cvt_st8(__bf16* d, f32x4 a, f32x4 b){
  bf16x8 v;
  v[0]=(__bf16)a.x; v[1]=(__bf16)a.y; v[2]=(__bf16)a.z; v[3]=(__bf16)a.w;
  v[4]=(__bf16)b.x; v[5]=(__bf16)b.y; v[6]=(__bf16)b.z; v[7]=(__bf16)b.w;
  *reinterpret_cast<bf16x8*>(d) = v;
}
__device__ __forceinline__ void gld_lds16(const void* g, void* l){
  __builtin_amdgcn_global_load_lds(
    (const __attribute__((address_space(1))) void*)g,
    (__attribute__((address_space(3))) void*)l, 16, 0, 0);
}
__device__ __forceinline__ int xcd_map(int orig, int nwg){
  int q = nwg>>3, rr = nwg&7, x = orig&7, o = orig>>3;
  return (x<rr ? x*(q+1) : rr*(q+1)+(x-rr)*q) + o;
}

// ======== fused gate + w1/w3 conversion (R17-proven) ========
#define GATEB (NTOK/8)              // 1024
#define CVTPB (NE*HID*DIM/16/256)   // 5632 blocks per tensor
__global__ __launch_bounds__(256) void k_cvtgate(
    const float* __restrict__ x,  const float* __restrict__ gw,
    const float* __restrict__ s1, const float* __restrict__ s3,
    __bf16* __restrict__ d1, __bf16* __restrict__ d3,
    int* __restrict__ idxs, float* __restrict__ wt, __bf16* __restrict__ xb)
{
  int tid = threadIdx.x;
  if(blockIdx.x >= GATEB){
    int cb  = blockIdx.x - GATEB;
    int seg = cb / CVTPB;
    size_t i = (size_t)(cb % CVTPB)*256 + tid;
    const float* src = (seg==0) ? s1 : s3;
    __bf16*      dst = (seg==0) ? d1 : d3;
    const f32x4* s = reinterpret_cast<const f32x4*>(src) + i*4;
    f32x4 a = __builtin_nontemporal_load(s);
    f32x4 b = __builtin_nontemporal_load(s+1);
    f32x4 c = __builtin_nontemporal_load(s+2);
    f32x4 d = __builtin_nontemporal_load(s+3);
    cvt_st8(dst + i*16,     a, b);
    cvt_st8(dst + i*16 + 8, c, d);
    return;
  }

  __shared__ double part[8][8][4];
  __shared__ double lg[8][8];

  int tl = tid>>5, e = (tid>>2)&7, q = tid&3;
  int t  = blockIdx.x*8 + tl;

  const f32x4* x4 = reinterpret_cast<const f32x4*>(x)  + (size_t)t*256 + q*64;
  const f32x4* g4 = reinterpret_cast<const f32x4*>(gw) + e*256 + q*64;

  double s0 = 0.0, s1d = 0.0;
#pragma unroll 4
  for(int j=0;j<64;j+=2){
    f32x4 a0 = x4[j],   b0 = g4[j];
    f32x4 a1 = x4[j+1], b1 = g4[j+1];
    s0  += (double)a0.x*b0.x + (double)a0.y*b0.y
         + (double)a0.z*b0.z + (double)a0.w*b0.w;
    s1d += (double)a1.x*b1.x + (double)a1.y*b1.y
         + (double)a1.z*b1.z + (double)a1.w*b1.w;
  }
  part[tl][e][q] = s0 + s1d;
  __syncthreads();
  if(q==0)
    lg[tl][e] = part[tl][e][0] + part[tl][e][1] + part[tl][e][2] + part[tl][e][3];
  __syncthreads();

  if(tid < 8){
    int tt = blockIdx.x*8 + tid;
    int i1=0; double m1=lg[tid][0];
#pragma unroll
    for(int k=1;k<NE;k++) if(lg[tid][k]>m1){ m1=lg[tid][k]; i1=k; }
    int i2=-1; double m2=-1e300;
#pragma unroll
    for(int k=0;k<NE;k++) if(k!=i1 && lg[tid][k]>m2){ m2=lg[tid][k]; i2=k; }
    float e2 = __expf((float)(m2-m1));
    float w0 = 1.f/(1.f+e2);
    idxs[2*tt]=i1; idxs[2*tt+1]=i2;
    wt[2*tt]=w0;   wt[2*tt+1]=e2*w0;
  }

  const f32x4* xs = reinterpret_cast<const f32x4*>(x) + (size_t)blockIdx.x*2048;
  __bf16* xo = xb + (size_t)blockIdx.x*8192;
#pragma unroll
  for(int k=0;k<4;k++){
    int c = k*256 + tid;
    cvt_st8(xo + (size_t)c*8, xs[2*c], xs[2*c+1]);
  }
}

// ---- prep: histogram + prefix for BOTH tile sizes ----
__global__ __launch_bounds__(256) void k_prep(const int* __restrict__ idxs,
    int* __restrict__ off, int* __restrict__ mtp, int* __restrict__ mtp2,
    int* __restrict__ cursor)
{
  __shared__ int hist[NE];
  int tid = threadIdx.x;
  if(tid < NE) hist[tid] = 0;
  __syncthreads();
  int local[NE] = {0,0,0,0,0,0,0,0};
  for(int k=0;k<NSLOT/256;k++){
    int e = idxs[tid*(NSLOT/256) + k];
    local[e]++;
  }
#pragma unroll
  for(int e=0;e<NE;e++) if(local[e]) atomicAdd(&hist[e], local[e]);
  __syncthreads();
  if(tid==0){
    int o=0, m=0, m2=0; off[0]=0; mtp[0]=0; mtp2[0]=0;
    for(int e=0;e<NE;e++){
      cursor[e]=o; o += hist[e]; off[e+1]=o;
      m  += (hist[e]+BM-1)>>7;   mtp[e+1]=m;
      m2 += (hist[e]+BM2-1)>>8;  mtp2[e+1]=m2;
    }
  }
}

__global__ __launch_bounds__(256) void k_scatter(const int* __restrict__ idxs,
    int* __restrict__ cursor, int* __restrict__ order, int* __restrict__ inv)
{
  int t = blockIdx.x*blockDim.x + threadIdx.x;
#pragma unroll
  for(int k=0;k<2;k++){
    int s = 2*t+k;
    int e = idxs[s];
    int p = atomicAdd(&cursor[e],1);
    order[p]=s; inv[s]=p;
  }
}

// ======== FFN1 (R17-proven): 128x128x2 2-phase + w2-cvt tail ========
#define FFN1B (MAXMT*(HID/128))     // 2992 GEMM blocks
#define CVT2B (NE*DIM*HID/16/512)   // 2816 cvt blocks
__global__ __launch_bounds__(512) void k_ffn1(
    const __bf16* __restrict__ xb, const __bf16* __restrict__ w1b,
    const __bf16* __restrict__ w3b, const int* __restrict__ off,
    const int* __restrict__ mtp, const int* __restrict__ order,
    __bf16* __restrict__ h, const float* __restrict__ w2src,
    __bf16* __restrict__ w2b)
{
  __shared__ __align__(16) __bf16 lA [2][BM*BK];
  __shared__ __align__(16) __bf16 lB1[2][BM*BK];
  __shared__ __align__(16) __bf16 lB3[2][BM*BK];

  int tid = threadIdx.x;
  if(blockIdx.x >= FFN1B){
    size_t i = (size_t)(blockIdx.x - FFN1B)*512 + tid;
    const f32x4* s = reinterpret_cast<const f32x4*>(w2src) + i*4;
    f32x4 a = __builtin_nontemporal_load(s);
    f32x4 b = __builtin_nontemporal_load(s+1);
    f32x4 c = __builtin_nontemporal_load(s+2);
    f32x4 d = __builtin_nontemporal_load(s+3);
    cvt_st8(w2b + i*16,     a, b);
    cvt_st8(w2b + i*16 + 8, c, d);
    return;
  }

  const int NT = HID/128;                // 22
  int wg = xcd_map(blockIdx.x, FFN1B);
  int mt = wg / NT, nt = wg % NT;
  if (mt >= mtp[NE]) return;
  int e = 0;
  while (mt >= mtp[e+1]) e++;
  int row0    = off[e] + (mt - mtp[e])*BM;
  int row_end = off[e+1];
  int n0      = nt*128;

  int lane = tid&63;
  int srow = tid>>2;
  int scol = ((tid&3) ^ ((srow>>1)&3))<<3;
  int arow = min(row0 + srow, row_end-1);
  int tok  = order[arow] >> 1;
  const __bf16* gA  = xb  + (size_t)tok*DIM + scol;
  const __bf16* gB1 = w1b + (size_t)e*HID*DIM + (size_t)(n0+srow)*DIM + scol;
  const __bf16* gB3 = w3b + (size_t)e*HID*DIM + (size_t)(n0+srow)*DIM + scol;
  int ldso = (tid>>6)<<9;

  int wm = (tid>>6)>>2, wn = (tid>>6)&3;
  int fr = lane & 15, gq = lane>>4;

  f32x4 acc1[4][2], acc3[4][2];
#pragma unroll
  for(int m=0;m<4;m++)
#pragma unroll
    for(int n=0;n<2;n++){ acc1[m][n]=f32x4{0.f,0.f,0.f,0.f}; acc3[m][n]=f32x4{0.f,0.f,0.f,0.f}; }

  gld_lds16(gA,  &lA [0][ldso]);
  gld_lds16(gB1, &lB1[0][ldso]);
  gld_lds16(gB3, &lB3[0][ldso]);
  __syncthreads();

  const int NK = DIM/BK;                 // 32
  int buf=0;
  for(int kt=0; kt<NK; kt++){
    if(kt+1<NK){
      gld_lds16(gA  + (kt+1)*BK, &lA [buf^1][ldso]);
      gld_lds16(gB1 + (kt+1)*BK, &lB1[buf^1][ldso]);
      gld_lds16(gB3 + (kt+1)*BK, &lB3[buf^1][ldso]);
    }
    bf16x8 av[4], bv[2], cv[2];
#pragma unroll
    for(int m=0;m<4;m++) av[m]=*reinterpret_cast<const bf16x8*>(&lA[buf][SWZ(wm*64+m*16+fr, gq)]);
#pragma unroll
    for(int n=0;n<2;n++){
      bv[n]=*reinterpret_cast<const bf16x8*>(&lB1[buf][SWZ(wn*32+n*16+fr, gq)]);
      cv[n]=*reinterpret_cast<const bf16x8*>(&lB3[buf][SWZ(wn*32+n*16+fr, gq)]);
    }
#pragma unroll
    for(int m=0;m<4;m++)
#pragma unroll
      for(int n=0;n<2;n++){
        acc1[m][n]=MFMA(av[m],bv[n],acc1[m][n]);
        acc3[m][n]=MFMA(av[m],cv[n],acc3[m][n]);
      }
    __syncthreads();
    buf^=1;
  }

#pragma unroll
  for(int m=0;m<4;m++){
    int rbase = row0 + wm*64 + m*16 + (gq<<2);
#pragma unroll
    for(int r=0;r<4;r++){
      if(rbase+r < row_end){
        __bf16* hp = h + (size_t)(rbase+r)*HID + n0 + wn*32 + fr;
#pragma unroll
        for(int n=0;n<2;n++){
          float u = acc1[m][n][r], v = acc3[m][n][r];
          hp[n*16] = (__bf16)( (u/(1.f+__expf(-u))) * v );
        }
      }
    }
  }
}

// ======== FFN2: m201-faithful 8-phase, 256x256, BK=64, 8 waves (2Mx4N) ========
// LDS 128KB = 2 tensors x [2 buf][2 rb][2 kk][128x32 swizzled].
// Stage unit = one [128][32] block = 1 gld issue; 2 issues/phase.
// vmcnt(8) at every even phase end: each read's unit is staged >=4 phases
// earlier and covered (full ledger in phase table below).
#define LIDX(buf, rb, kk) (((((buf)*2 + (rb))*2 + (kk))<<12))
__global__ __launch_bounds__(512) void k_ffn2(
    const __bf16* __restrict__ h, const __bf16* __restrict__ w2b,
    const int* __restrict__ off, const int* __restrict__ mtp2,
    __bf16* __restrict__ ys)
{
  __shared__ __align__(16) __bf16 lA[2*2*2*4096];   // 64 KB
  __shared__ __align__(16) __bf16 lB[2*2*2*4096];   // 64 KB

  const int NT = DIM/256;                // 4
  int wg = xcd_map(blockIdx.x, MAXMT2*NT);
  int mt = wg / NT, nt = wg % NT;
  if (mt >= mtp2[NE]) return;
  int e = 0;
  while (mt >= mtp2[e+1]) e++;
  int row0    = off[e] + (mt - mtp2[e])*BM2;
  int row_end = off[e+1];
  int n0      = nt*256;

  int tid = threadIdx.x, lane = tid&63, wave = tid>>6;  // 8 waves
  int wm = wave>>2, wn = wave&3;         // 2Mx4N; wave tile 128x64
  int fr = lane&15, gq = lane>>4;

  int sr = tid>>2, gloc = tid&3;         // staging: 128 rows x 4 granules
  int scol = ((gloc ^ ((sr>>1)&3))<<3);  // pre-swizzled source granule
  int hr0 = min(row0 + sr,       NSLOT-1);
  int hr1 = min(row0 + 128 + sr, NSLOT-1);
  const __bf16* gA0 = h   + (size_t)hr0*HID + scol;
  const __bf16* gA1 = h   + (size_t)hr1*HID + scol;
  const __bf16* gB0 = w2b + (size_t)e*DIM*HID + (size_t)(n0+sr)*HID + scol;
  const __bf16* gB1 = w2b + (size_t)e*DIM*HID + (size_t)(n0+128+sr)*HID + scol;
  int ldso = wave<<9;                    // per-wave 512-elem slice of a block

  f32x4 acc[8][4];
#pragma unroll
  for(int m=0;m<8;m++)
#pragma unroll
    for(int n=0;n<4;n++) acc[m][n]=f32x4{0.f,0.f,0.f,0.f};

  // stage one [128][32] unit pair: tensor T, dest (buf, kk), K-tile kt_
#define STG_A(buf, kk, kt_) { \
    gld_lds16(gA0 + (size_t)(kt_)*BK2 + (kk)*32, &lA[LIDX(buf,0,kk)+ldso]); \
    gld_lds16(gA1 + (size_t)(kt_)*BK2 + (kk)*32, &lA[LIDX(buf,1,kk)+ldso]); }
#define STG_B(buf, kk, kt_) { \
    gld_lds16(gB0 + (size_t)(kt_)*BK2 + (kk)*32, &lB[LIDX(buf,0,kk)+ldso]); \
    gld_lds16(gB1 + (size_t)(kt_)*BK2 + (kk)*32, &lB[LIDX(buf,1,kk)+ldso]); }

  // phase: read (buf,kk) fragments for m-half mh; RB=reload bv; 16 MFMA
#define PH(buf, kk, mh, RB, STAGE, WAITC) { \
    bf16x8 av[4]; \
    _Pragma("unroll") for(int m_=0;m_<4;m_++) \
      av[m_] = *(const bf16x8*)&lA[LIDX(buf,wm,kk) + SWZ(((mh)*4+m_)*16 + fr, gq)]; \
    if(RB){ _Pragma("unroll") for(int n_=0;n_<4;n_++) \
      bv[n_] = *(const bf16x8*)&lB[LIDX(buf,(wn>>1),kk) + SWZ((wn&1)*64 + n_*16 + fr, gq)]; } \
    STAGE; \
    __builtin_amdgcn_s_barrier(); \
    asm volatile("s_waitcnt lgkmcnt(0)" ::: "memory"); \
    __builtin_amdgcn_sched_barrier(0); \
    __builtin_amdgcn_s_setprio(1); \
    _Pragma("unroll") for(int m_=0;m_<4;m_++) _Pragma("unroll") for(int n_=0;n_<4;n_++) \
      acc[(mh)*4+m_][n_] = MFMA(av[m_], bv[n_], acc[(mh)*4+m_][n_]); \
    __builtin_amdgcn_s_setprio(0); \
    WAITC; \
    __builtin_amdgcn_s_barrier(); }

  // prologue: t0 fully (Akk0,Bkk0,Akk1,Bkk1) + t1 kk0 (A,B) = 12 issues.
  // VMW(8): first 4 (t0 kk0) landed; 8 in flight = steady-state invariant.
  STG_A(0,0,0); STG_B(0,0,0); STG_A(0,1,0); STG_B(0,1,0);
  STG_A(1,0,1); STG_B(1,0,1);
  VMW(8);
  __builtin_amdgcn_s_barrier();

  bf16x8 bv[4];
  int kt = 0;
  const int NTI = (HID/BK2)/2;           // 22 iterations (44 K-tiles)
  // phase table (iteration i: tile kt->b0 read ph1-4, kt+1->b1 read ph5-8):
  //   ph1 stage b1.A.kk1 (t kt+1, read ph7)   ph2 stage b1.B.kk1; VMW(8)
  //   ph3 stage b0.A.kk0 (t kt+2, read ph1')  ph4 stage b0.B.kk0; VMW(8)
  //   ph5 stage b0.A.kk1 (read ph3')          ph6 stage b0.B.kk1; VMW(8)
  //   ph7 stage b1.A.kk0 (t kt+3, read ph5')  ph8 stage b1.B.kk0; VMW(8)
  // each VMW(8) leaves only the last 2 phases' 4 issues outstanding ->
  // every read's unit (staged >=4 phases before) is landed.
  for(int it=0; it<NTI-1; ++it, kt+=2){
    PH(0,0,0, 1, STG_A(1,1,kt+1), NOP);
    PH(0,0,1, 0, STG_B(1,1,kt+1), VMW(8));
    PH(0,1,0, 1, STG_A(0,0,kt+2), NOP);
    PH(0,1,1, 0, STG_B(0,0,kt+2), VMW(8));
    PH(1,0,0, 1, STG_A(0,1,kt+2), NOP);
    PH(1,0,1, 0, STG_B(0,1,kt+2), VMW(8));
    PH(1,1,0, 1, STG_A(1,0,kt+3), NOP);
    PH(1,1,1, 0, STG_B(1,0,kt+3), VMW(8));
  }
  // peeled last iteration (kt=42): only t43.kk1 staged; tightened waits
  PH(0,0,0, 1, STG_A(1,1,kt+1), NOP);
  PH(0,0,1, 0, STG_B(1,1,kt+1), VMW(8));
  PH(0,1,0, 1, NOP, NOP);
  PH(0,1,1, 0, NOP, VMW(4));   // forces prev-iter ph7,8 (t43.kk0) landed
  PH(1,0,0, 1, NOP, NOP);
  PH(1,0,1, 0, NOP, VMW(0));   // forces ph1,2 (t43.kk1) landed
  PH(1,1,0, 1, NOP, NOP);
  PH(1,1,1, 0, NOP, NOP);
#undef STG_A
#undef STG_B
#undef PH

  // epilogue: per-slot bf16 ys, masked at segment end
#pragma unroll
  for(int m=0;m<8;m++){
    int rbase = row0 + wm*128 + m*16 + (gq<<2);
#pragma unroll
    for(int r=0;r<4;r++){
      if(rbase+r < row_end){
        __bf16* yp = ys + (size_t)(rbase+r)*DIM + n0 + wn*64 + fr;
#pragma unroll
        for(int n=0;n<4;n++) yp[n*16] = (__bf16)acc[m][n][r];
      }
    }
  }
}

// ---------------- weighted combine (fully overwrites y) ----------------
__global__ __launch_bounds__(256) void k_combine(
    const __bf16* __restrict__ ys, const int* __restrict__ inv,
    const float* __restrict__ wt, float* __restrict__ y)
{
  int t  = blockIdx.x;
  int p0 = inv[2*t], p1 = inv[2*t+1];
  float w0 = wt[2*t], w1v = wt[2*t+1];
  int d = threadIdx.x*4;
  const __bf16* r0 = ys + (size_t)p0*DIM + d;
  const __bf16* r1 = ys + (size_t)p1*DIM + d;
  f32x4 o;
#pragma unroll
  for(int j=0;j<4;j++) o[j] = w0*(float)r0[j] + w1v*(float)r1[j];
  *reinterpret_cast<f32x4*>(y + (size_t)t*DIM + d) = o;
}

// ---------------- launch ----------------
extern "C" void kernel_launch(void* const* d_in, const int* in_sizes, int n_in,
                              void* d_out, int out_size, void* d_ws, size_t ws_size,
                              hipStream_t stream)
{
  const float* x  = (const float*)d_in[0];
  const float* gw = (const float*)d_in[1];
  const float* w1 = (const float*)d_in[2];
  const float* w3 = (const float*)d_in[3];
  const float* w2 = (const float*)d_in[4];
  float* y = (float*)d_out;
  char* ws = (char*)d_ws;

  int*   off    = (int*)(ws + 64);
  int*   mtp    = (int*)(ws + 128);
  int*   mtp2   = (int*)(ws + 192);
  int*   cursor = (int*)(ws + 256);
  int*   idxs   = (int*)(ws + 320);
  float* wt     = (float*)(ws + 320 + 65536);
  int*   order  = (int*)(ws + 320 + 2*65536);
  int*   inv    = (int*)(ws + 320 + 3*65536);
  __bf16* h     = (__bf16*)(ws + 262464);
  __bf16* xb    = (__bf16*)(ws + 262464 + 92274688ull);
  __bf16* w1b   = (__bf16*)(ws + 262464 + 92274688ull + 16777216ull);
  __bf16* w3b   = (__bf16*)(ws + 262464 + 92274688ull + 16777216ull + 46137344ull);
  __bf16* w2b   = (__bf16*)(ws + 262464 + 92274688ull + 16777216ull + 2*46137344ull);
  __bf16* ysb   = w1b;   // dead after k_ffn1 -> reuse

  k_cvtgate<<<GATEB + 2*CVTPB, 256, 0, stream>>>(x, gw, w1, w3,
                                                 w1b, w3b, idxs, wt, xb);
  k_prep   <<<1, 256, 0, stream>>>(idxs, off, mtp, mtp2, cursor);
  k_scatter<<<NTOK/256, 256, 0, stream>>>(idxs, cursor, order, inv);
  k_ffn1   <<<FFN1B + CVT2B, 512, 0, stream>>>(xb, w1b, w3b, off, mtp, order,
                                               h, w2, w2b);
  k_ffn2   <<<MAXMT2*(DIM/256), 512, 0, stream>>>(h, w2b, off, mtp2, ysb);
  k_combine<<<NTOK, 256, 0, stream>>>(ysb, inv, wt, y);
}

// Round 19
// 615.620 us; speedup vs baseline: 1.0437x; 1.0437x over previous
//
#include <hip/hip_runtime.h>
#include <hip/hip_bf16.h>

#define NTOK 8192
#define DIM 1024
#define HID 2816
#define NE 8
#define NSLOT (NTOK*2)
#define BM 128
#define BK 32
#define MAXMT (NSLOT/BM + NE)   // 136 worst-case M-tiles @ BM=128

typedef float f32x4 __attribute__((ext_vector_type(4)));
typedef __bf16 bf16x8 __attribute__((ext_vector_type(8)));
typedef __bf16 bf16x4 __attribute__((ext_vector_type(4)));

#define MFMA(a,b,c) __builtin_amdgcn_mfma_f32_16x16x32_bf16(a,b,c,0,0,0)
// element index in a linear [rows][32] bf16 tile, XOR bank swizzle (R2-proven: 0 conflicts)
#define SWZ(r,g) (((r)<<5) + ((((g) ^ (((r)>>1)&3)))<<3))

__device__ __forceinline__ void cvt_st8(__bf16* d, f32x4 a, f32x4 b){
  bf16x8 v;
  v[0]=(__bf16)a.x; v[1]=(__bf16)a.y; v[2]=(__bf16)a.z; v[3]=(__bf16)a.w;
  v[4]=(__bf16)b.x; v[5]=(__bf16)b.y; v[6]=(__bf16)b.z; v[7]=(__bf16)b.w;
  *reinterpret_cast<bf16x8*>(d) = v;
}
__device__ __forceinline__ void gld_lds16(const void* g, void* l){
  __builtin_amdgcn_global_load_lds(
    (const __attribute__((address_space(1))) void*)g,
    (__attribute__((address_space(3))) void*)l, 16, 0, 0);
}
__device__ __forceinline__ int xcd_map(int orig, int nwg){
  int q = nwg>>3, rr = nwg&7, x = orig&7, o = orig>>3;
  return (x<rr ? x*(q+1) : rr*(q+1)+(x-rr)*q) + o;
}

// ======== fused gate + w1/w3 conversion (R17-proven) ========
#define GATEB (NTOK/8)              // 1024
#define CVTPB (NE*HID*DIM/16/256)   // 5632 blocks per tensor
__global__ __launch_bounds__(256) void k_cvtgate(
    const float* __restrict__ x,  const float* __restrict__ gw,
    const float* __restrict__ s1, const float* __restrict__ s3,
    __bf16* __restrict__ d1, __bf16* __restrict__ d3,
    int* __restrict__ idxs, float* __restrict__ wt, __bf16* __restrict__ xb)
{
  int tid = threadIdx.x;
  if(blockIdx.x >= GATEB){
    int cb  = blockIdx.x - GATEB;
    int seg = cb / CVTPB;
    size_t i = (size_t)(cb % CVTPB)*256 + tid;   // unit of 16 f32
    const float* src = (seg==0) ? s1 : s3;
    __bf16*      dst = (seg==0) ? d1 : d3;
    const f32x4* s = reinterpret_cast<const f32x4*>(src) + i*4;
    f32x4 a = __builtin_nontemporal_load(s);     // fp32 source is read-once
    f32x4 b = __builtin_nontemporal_load(s+1);
    f32x4 c = __builtin_nontemporal_load(s+2);
    f32x4 d = __builtin_nontemporal_load(s+3);
    cvt_st8(dst + i*16,     a, b);
    cvt_st8(dst + i*16 + 8, c, d);
    return;
  }

  // ---- gating section (R7-proven lane-parallel f64 dots) ----
  __shared__ double part[8][8][4];
  __shared__ double lg[8][8];

  int tl = tid>>5, e = (tid>>2)&7, q = tid&3;
  int t  = blockIdx.x*8 + tl;

  const f32x4* x4 = reinterpret_cast<const f32x4*>(x)  + (size_t)t*256 + q*64;
  const f32x4* g4 = reinterpret_cast<const f32x4*>(gw) + e*256 + q*64;

  double s0 = 0.0, s1d = 0.0;
#pragma unroll 4
  for(int j=0;j<64;j+=2){
    f32x4 a0 = x4[j],   b0 = g4[j];
    f32x4 a1 = x4[j+1], b1 = g4[j+1];
    s0  += (double)a0.x*b0.x + (double)a0.y*b0.y
         + (double)a0.z*b0.z + (double)a0.w*b0.w;
    s1d += (double)a1.x*b1.x + (double)a1.y*b1.y
         + (double)a1.z*b1.z + (double)a1.w*b1.w;
  }
  part[tl][e][q] = s0 + s1d;
  __syncthreads();
  if(q==0)
    lg[tl][e] = part[tl][e][0] + part[tl][e][1] + part[tl][e][2] + part[tl][e][3];
  __syncthreads();

  if(tid < 8){
    int tt = blockIdx.x*8 + tid;
    int i1=0; double m1=lg[tid][0];
#pragma unroll
    for(int k=1;k<NE;k++) if(lg[tid][k]>m1){ m1=lg[tid][k]; i1=k; }
    int i2=-1; double m2=-1e300;
#pragma unroll
    for(int k=0;k<NE;k++) if(k!=i1 && lg[tid][k]>m2){ m2=lg[tid][k]; i2=k; }
    float e2 = __expf((float)(m2-m1));
    float w0 = 1.f/(1.f+e2);
    idxs[2*tt]=i1; idxs[2*tt+1]=i2;
    wt[2*tt]=w0;   wt[2*tt+1]=e2*w0;
  }

  const f32x4* xs = reinterpret_cast<const f32x4*>(x) + (size_t)blockIdx.x*2048;
  __bf16* xo = xb + (size_t)blockIdx.x*8192;
#pragma unroll
  for(int k=0;k<4;k++){
    int c = k*256 + tid;
    cvt_st8(xo + (size_t)c*8, xs[2*c], xs[2*c+1]);
  }
}

// ---- prep: histogram idxs -> cnt, then serial prefix (R16-proven) ----
__global__ __launch_bounds__(256) void k_prep(const int* __restrict__ idxs,
    int* __restrict__ off, int* __restrict__ mtp, int* __restrict__ cursor)
{
  __shared__ int hist[NE];
  int tid = threadIdx.x;
  if(tid < NE) hist[tid] = 0;
  __syncthreads();
  int local[NE] = {0,0,0,0,0,0,0,0};
  for(int k=0;k<NSLOT/256;k++){
    int e = idxs[tid*(NSLOT/256) + k];
    local[e]++;
  }
#pragma unroll
  for(int e=0;e<NE;e++) if(local[e]) atomicAdd(&hist[e], local[e]);
  __syncthreads();
  if(tid==0){
    int o=0, m=0; off[0]=0; mtp[0]=0;
    for(int e=0;e<NE;e++){
      cursor[e]=o; o += hist[e]; off[e+1]=o;
      m += (hist[e]+BM-1)/BM;  mtp[e+1]=m;
    }
  }
}

__global__ __launch_bounds__(256) void k_scatter(const int* __restrict__ idxs,
    int* __restrict__ cursor, int* __restrict__ order, int* __restrict__ inv)
{
  int t = blockIdx.x*blockDim.x + threadIdx.x;
#pragma unroll
  for(int k=0;k<2;k++){
    int s = 2*t+k;
    int e = idxs[s];
    int p = atomicAdd(&cursor[e],1);
    order[p]=s; inv[s]=p;
  }
}

// ======== FFN1 (R17-proven): 128x128x2 2-phase + w2-cvt tail ========
#define FFN1B (MAXMT*(HID/128))     // 2992 GEMM blocks
#define CVT2B (NE*DIM*HID/16/512)   // 2816 cvt blocks
__global__ __launch_bounds__(512) void k_ffn1(
    const __bf16* __restrict__ xb, const __bf16* __restrict__ w1b,
    const __bf16* __restrict__ w3b, const int* __restrict__ off,
    const int* __restrict__ mtp, const int* __restrict__ order,
    __bf16* __restrict__ h, const float* __restrict__ w2src,
    __bf16* __restrict__ w2b)
{
  __shared__ __align__(16) __bf16 lA [2][BM*BK];
  __shared__ __align__(16) __bf16 lB1[2][BM*BK];
  __shared__ __align__(16) __bf16 lB3[2][BM*BK];

  int tid = threadIdx.x;
  if(blockIdx.x >= FFN1B){
    // w2 fp32->bf16 in ffn1's tail; complete before kernel end -> safe for ffn2
    size_t i = (size_t)(blockIdx.x - FFN1B)*512 + tid;
    const f32x4* s = reinterpret_cast<const f32x4*>(w2src) + i*4;
    f32x4 a = __builtin_nontemporal_load(s);
    f32x4 b = __builtin_nontemporal_load(s+1);
    f32x4 c = __builtin_nontemporal_load(s+2);
    f32x4 d = __builtin_nontemporal_load(s+3);
    cvt_st8(w2b + i*16,     a, b);
    cvt_st8(w2b + i*16 + 8, c, d);
    return;
  }

  const int NT = HID/128;                // 22
  int wg = xcd_map(blockIdx.x, FFN1B);
  int mt = wg / NT, nt = wg % NT;
  if (mt >= mtp[NE]) return;
  int e = 0;
  while (mt >= mtp[e+1]) e++;
  int row0    = off[e] + (mt - mtp[e])*BM;
  int row_end = off[e+1];
  int n0      = nt*128;

  int lane = tid&63;
  int srow = tid>>2;
  int scol = ((tid&3) ^ ((srow>>1)&3))<<3;   // pre-swizzled source granule
  int arow = min(row0 + srow, row_end-1);
  int tok  = order[arow] >> 1;
  const __bf16* gA  = xb  + (size_t)tok*DIM + scol;
  const __bf16* gB1 = w1b + (size_t)e*HID*DIM + (size_t)(n0+srow)*DIM + scol;
  const __bf16* gB3 = w3b + (size_t)e*HID*DIM + (size_t)(n0+srow)*DIM + scol;
  int ldso = (tid>>6)<<9;                // wave * 512 elements (1KB)

  int wm = (tid>>6)>>2, wn = (tid>>6)&3; // 2x4 wave grid, wave tile 64x32 (x2 tensors)
  int fr = lane & 15, gq = lane>>4;

  f32x4 acc1[4][2], acc3[4][2];
#pragma unroll
  for(int m=0;m<4;m++)
#pragma unroll
    for(int n=0;n<2;n++){ acc1[m][n]=f32x4{0.f,0.f,0.f,0.f}; acc3[m][n]=f32x4{0.f,0.f,0.f,0.f}; }

  gld_lds16(gA,  &lA [0][ldso]);
  gld_lds16(gB1, &lB1[0][ldso]);
  gld_lds16(gB3, &lB3[0][ldso]);
  __syncthreads();

  const int NK = DIM/BK;                 // 32
  int buf=0;
  for(int kt=0; kt<NK; kt++){
    if(kt+1<NK){
      gld_lds16(gA  + (kt+1)*BK, &lA [buf^1][ldso]);
      gld_lds16(gB1 + (kt+1)*BK, &lB1[buf^1][ldso]);
      gld_lds16(gB3 + (kt+1)*BK, &lB3[buf^1][ldso]);
    }
    bf16x8 av[4], bv[2], cv[2];
#pragma unroll
    for(int m=0;m<4;m++) av[m]=*reinterpret_cast<const bf16x8*>(&lA[buf][SWZ(wm*64+m*16+fr, gq)]);
#pragma unroll
    for(int n=0;n<2;n++){
      bv[n]=*reinterpret_cast<const bf16x8*>(&lB1[buf][SWZ(wn*32+n*16+fr, gq)]);
      cv[n]=*reinterpret_cast<const bf16x8*>(&lB3[buf][SWZ(wn*32+n*16+fr, gq)]);
    }
#pragma unroll
    for(int m=0;m<4;m++)
#pragma unroll
      for(int n=0;n<2;n++){
        acc1[m][n]=MFMA(av[m],bv[n],acc1[m][n]);
        acc3[m][n]=MFMA(av[m],cv[n],acc3[m][n]);
      }
    __syncthreads();
    buf^=1;
  }

#pragma unroll
  for(int m=0;m<4;m++){
    int rbase = row0 + wm*64 + m*16 + (gq<<2);
#pragma unroll
    for(int r=0;r<4;r++){
      if(rbase+r < row_end){
        __bf16* hp = h + (size_t)(rbase+r)*HID + n0 + wn*32 + fr;
#pragma unroll
        for(int n=0;n<2;n++){
          float u = acc1[m][n][r], v = acc3[m][n][r];
          hp[n*16] = (__bf16)( (u/(1.f+__expf(-u))) * v );
        }
      }
    }
  }
}

// ======== FFN2 (R15/R16-proven): ys = h @ w2^T, 128x128, 256 thr, dbuf ========
__global__ __launch_bounds__(256) void k_ffn2(
    const __bf16* __restrict__ h, const __bf16* __restrict__ w2b,
    const int* __restrict__ off, const int* __restrict__ mtp,
    __bf16* __restrict__ ys)
{
  __shared__ __align__(16) __bf16 lA[2][128*BK];    // 8 KB per buf
  __shared__ __align__(16) __bf16 lB[2][128*BK];

  const int NT = DIM/128;                // 8
  int wg = xcd_map(blockIdx.x, MAXMT*NT);
  int mt = wg / NT, nt = wg % NT;
  if (mt >= mtp[NE]) return;
  int e = 0;
  while (mt >= mtp[e+1]) e++;
  int row0    = off[e] + (mt - mtp[e])*BM;
  int row_end = off[e+1];
  int n0      = nt*128;

  int tid = threadIdx.x, lane = tid&63, wave = tid>>6;  // 4 waves
  int srow = tid>>2;                     // 0..63
  int scol = ((tid&3) ^ ((srow>>1)&3))<<3;   // same XOR phase valid for srow+64 (64%8==0)
  int hr0 = min(row0 + srow,      NSLOT-1);
  int hr1 = min(row0 + srow + 64, NSLOT-1);
  const __bf16* gA0 = h   + (size_t)hr0*HID + scol;
  const __bf16* gA1 = h   + (size_t)hr1*HID + scol;
  const __bf16* gB0 = w2b + (size_t)e*DIM*HID + (size_t)(n0+srow)*HID + scol;
  const __bf16* gB1 = w2b + (size_t)e*DIM*HID + (size_t)(n0+srow+64)*HID + scol;
  int ldso = wave<<9;                    // wave * 512 elements (1KB)

  int wm = wave>>1, wn = wave&1;         // 2x2 wave grid; wave tile 64(M)x64(N)
  int fr = lane&15, gq = lane>>4;

  f32x4 acc[4][4];
#pragma unroll
  for(int m=0;m<4;m++)
#pragma unroll
    for(int n=0;n<4;n++) acc[m][n]=f32x4{0.f,0.f,0.f,0.f};

  gld_lds16(gA0, &lA[0][ldso]);
  gld_lds16(gA1, &lA[0][2048+ldso]);
  gld_lds16(gB0, &lB[0][ldso]);
  gld_lds16(gB1, &lB[0][2048+ldso]);
  __syncthreads();

  const int NK = HID/BK;                 // 88
  int buf=0;
  for(int kt=0; kt<NK; kt++){
    if(kt+1<NK){
      gld_lds16(gA0 + (kt+1)*BK, &lA[buf^1][ldso]);
      gld_lds16(gA1 + (kt+1)*BK, &lA[buf^1][2048+ldso]);
      gld_lds16(gB0 + (kt+1)*BK, &lB[buf^1][ldso]);
      gld_lds16(gB1 + (kt+1)*BK, &lB[buf^1][2048+ldso]);
    }
    bf16x8 av[4], bv[4];
#pragma unroll
    for(int m=0;m<4;m++) av[m]=*reinterpret_cast<const bf16x8*>(&lA[buf][SWZ(wm*64+m*16+fr, gq)]);
#pragma unroll
    for(int n=0;n<4;n++) bv[n]=*reinterpret_cast<const bf16x8*>(&lB[buf][SWZ(wn*64+n*16+fr, gq)]);
#pragma unroll
    for(int m=0;m<4;m++)
#pragma unroll
      for(int n=0;n<4;n++)
        acc[m][n]=MFMA(av[m],bv[n],acc[m][n]);
    __syncthreads();
    buf^=1;
  }

  // epilogue: per-slot bf16 ys (no atomics)
#pragma unroll
  for(int m=0;m<4;m++){
    int rbase = row0 + wm*64 + m*16 + (gq<<2);
#pragma unroll
    for(int r=0;r<4;r++){
      if(rbase+r < row_end){
        __bf16* yp = ys + (size_t)(rbase+r)*DIM + n0 + wn*64 + fr;
#pragma unroll
        for(int n=0;n<4;n++) yp[n*16] = (__bf16)acc[m][n][r];
      }
    }
  }
}

// ---------------- weighted combine (fully overwrites y) ----------------
__global__ __launch_bounds__(256) void k_combine(
    const __bf16* __restrict__ ys, const int* __restrict__ inv,
    const float* __restrict__ wt, float* __restrict__ y)
{
  int t  = blockIdx.x;
  int p0 = inv[2*t], p1 = inv[2*t+1];
  float w0 = wt[2*t], w1v = wt[2*t+1];
  int d = threadIdx.x*4;
  const __bf16* r0 = ys + (size_t)p0*DIM + d;
  const __bf16* r1 = ys + (size_t)p1*DIM + d;
  f32x4 o;
#pragma unroll
  for(int j=0;j<4;j++) o[j] = w0*(float)r0[j] + w1v*(float)r1[j];
  *reinterpret_cast<f32x4*>(y + (size_t)t*DIM + d) = o;
}

// ---------------- launch ----------------
extern "C" void kernel_launch(void* const* d_in, const int* in_sizes, int n_in,
                              void* d_out, int out_size, void* d_ws, size_t ws_size,
                              hipStream_t stream)
{
  const float* x  = (const float*)d_in[0];
  const float* gw = (const float*)d_in[1];
  const float* w1 = (const float*)d_in[2];
  const float* w3 = (const float*)d_in[3];
  const float* w2 = (const float*)d_in[4];
  float* y = (float*)d_out;
  char* ws = (char*)d_ws;

  int*   off    = (int*)(ws + 64);
  int*   mtp    = (int*)(ws + 128);
  int*   cursor = (int*)(ws + 256);
  int*   idxs   = (int*)(ws + 320);
  float* wt     = (float*)(ws + 320 + 65536);
  int*   order  = (int*)(ws + 320 + 2*65536);
  int*   inv    = (int*)(ws + 320 + 3*65536);
  __bf16* h     = (__bf16*)(ws + 262464);
  __bf16* xb    = (__bf16*)(ws + 262464 + 92274688ull);
  __bf16* w1b   = (__bf16*)(ws + 262464 + 92274688ull + 16777216ull);
  __bf16* w3b   = (__bf16*)(ws + 262464 + 92274688ull + 16777216ull + 46137344ull);
  __bf16* w2b   = (__bf16*)(ws + 262464 + 92274688ull + 16777216ull + 2*46137344ull);
  __bf16* ysb   = w1b;   // dead after k_ffn1 -> reuse (33.5MB <= 46MB)

  k_cvtgate<<<GATEB + 2*CVTPB, 256, 0, stream>>>(x, gw, w1, w3,
                                                 w1b, w3b, idxs, wt, xb);
  k_prep   <<<1, 256, 0, stream>>>(idxs, off, mtp, cursor);
  k_scatter<<<NTOK/256, 256, 0, stream>>>(idxs, cursor, order, inv);
  k_ffn1   <<<FFN1B + CVT2B, 512, 0, stream>>>(xb, w1b, w3b, off, mtp, order,
                                               h, w2, w2b);
  k_ffn2   <<<MAXMT*(DIM/128), 256, 0, stream>>>(h, w2b, off, mtp, ysb);
  k_combine<<<NTOK, 256, 0, stream>>>(ysb, inv, wt, y);
}